// Round 9
// baseline (78812.598 us; speedup 1.0000x reference)
//
#include <hip/hip_runtime.h>
#include <math.h>

// PhysicsLSGStep: bitwise-faithful f32 replication of the numpy reference.
// Model (H11 = R5 + reduce-init fix):
// - np.add.at scatters: per-(node,feat) sequential f32 accumulation in edge
//   order (stable CSR); slope_n same (f32 sequential, shared across feats).
// - np.sum: accumulator initialized from FIRST ELEMENT (skip_first_count
//   semantics), then numpy pairwise_sum tree over the remaining n-1
//   (8-acc base blocks <=128, n2 -= n2%8 splits).
// - elementwise: f32, __f*_rn, no FMA contraction; alpha/beta pure f32.

#define F 8
#define CG_ITERS 30
#define LEAF_T 4096

#define S_RS    0
#define S_ALPHA 1
#define S_BETA  2
#define S_DONE  3
#define S_DONE2 4

__device__ __forceinline__ float dt_eff_of(const float* dtp) {
    return fminf(fmaxf(dtp[0], 0.02f), 2.0f);
}

// ---------- numpy pairwise sum replication (sum of a[i]*b[i]) ----------

__device__ float pw_base(const float* a, const float* b, int n) {
    if (n < 8) {
        float res = 0.f;
        for (int i = 0; i < n; ++i) res = __fadd_rn(res, __fmul_rn(a[i], b[i]));
        return res;
    }
    float r0 = __fmul_rn(a[0], b[0]);
    float r1 = __fmul_rn(a[1], b[1]);
    float r2 = __fmul_rn(a[2], b[2]);
    float r3 = __fmul_rn(a[3], b[3]);
    float r4 = __fmul_rn(a[4], b[4]);
    float r5 = __fmul_rn(a[5], b[5]);
    float r6 = __fmul_rn(a[6], b[6]);
    float r7 = __fmul_rn(a[7], b[7]);
    int i = 8;
    int lim = n - (n & 7);
    for (; i < lim; i += 8) {
        r0 = __fadd_rn(r0, __fmul_rn(a[i + 0], b[i + 0]));
        r1 = __fadd_rn(r1, __fmul_rn(a[i + 1], b[i + 1]));
        r2 = __fadd_rn(r2, __fmul_rn(a[i + 2], b[i + 2]));
        r3 = __fadd_rn(r3, __fmul_rn(a[i + 3], b[i + 3]));
        r4 = __fadd_rn(r4, __fmul_rn(a[i + 4], b[i + 4]));
        r5 = __fadd_rn(r5, __fmul_rn(a[i + 5], b[i + 5]));
        r6 = __fadd_rn(r6, __fmul_rn(a[i + 6], b[i + 6]));
        r7 = __fadd_rn(r7, __fmul_rn(a[i + 7], b[i + 7]));
    }
    float res = __fadd_rn(__fadd_rn(__fadd_rn(r0, r1), __fadd_rn(r2, r3)),
                          __fadd_rn(__fadd_rn(r4, r5), __fadd_rn(r6, r7)));
    for (; i < n; ++i) res = __fadd_rn(res, __fmul_rn(a[i], b[i]));
    return res;
}

// exact np recursion over a segment (n <= LEAF_T), iterative.
// off0 is a PHYSICAL index into a/b.
__device__ float pw_seg(const float* a, const float* b, int off0, int n0) {
    int soff[24], sn[24], sst[24]; float slv[24];
    int sp = 0;
    int coff = off0, cn = n0;
    for (;;) {
        if (cn <= 128) {
            float val = pw_base(a + coff, b + coff, cn);
            for (;;) {
                if (sp == 0) return val;
                if (sst[sp - 1] == 0) {
                    sst[sp - 1] = 1; slv[sp - 1] = val;
                    int n2 = sn[sp - 1] / 2; n2 -= (n2 & 7);
                    coff = soff[sp - 1] + n2; cn = sn[sp - 1] - n2;
                    break;
                } else {
                    val = __fadd_rn(slv[sp - 1], val);
                    sp--;
                }
            }
        } else {
            soff[sp] = coff; sn[sp] = cn; sst[sp] = 0; sp++;
            int n2 = cn / 2; n2 -= (n2 & 7);
            cn = n2;
        }
    }
}

// leaf decomposition of the VIRTUAL array of length n (= NF-1, starting at
// physical index 1); leafOff are virtual offsets.
__global__ void k_build_leaves(int n, int* leafOff, int* leafN, int* nLeaf) {
    if (threadIdx.x != 0 || blockIdx.x != 0) return;
    int spOff[40], spN[40]; int sp = 0;
    spOff[0] = 0; spN[0] = n;
    int cnt = 0;
    while (sp >= 0) {
        int off = spOff[sp], nn = spN[sp]; sp--;
        if (nn <= LEAF_T) {
            if (cnt < 2048) { leafOff[cnt] = off; leafN[cnt] = nn; }
            cnt++;
        } else {
            int n2 = nn / 2; n2 -= (n2 & 7);
            spOff[++sp] = off + n2; spN[sp] = nn - n2;  // right (popped second)
            spOff[++sp] = off;      spN[sp] = n2;       // left  (popped first)
        }
    }
    *nLeaf = cnt;
}

__global__ void k_dot_leaf(const float* a, const float* b, const int* leafOff,
                           const int* leafN, const int* nLeaf, float* partial) {
    int j = blockIdx.x * blockDim.x + threadIdx.x;
    if (j >= *nLeaf) return;
    partial[j] = pw_seg(a, b, leafOff[j] + 1, leafN[j]);  // +1: skip-first
}

// replay upper tree over leaf partials (virtual length n = NF-1), then
// total = (a[0]*b[0]) + tree  (numpy reduce: acc init from first element);
// then scalar update per mode.
__global__ void k_dot_combine(const float* a, const float* b,
                              const float* partial, int n, int mode, float* scal) {
    if (threadIdx.x != 0 || blockIdx.x != 0) return;
    int cnt = 0;
    int sn[40], sst[40]; float slv[40];
    int sp = 0; int cn = n;
    float res;
    for (;;) {
        if (cn <= LEAF_T) {
            float val = partial[cnt++];
            bool ret = false;
            for (;;) {
                if (sp == 0) { res = val; ret = true; break; }
                if (sst[sp - 1] == 0) {
                    sst[sp - 1] = 1; slv[sp - 1] = val;
                    int n2 = sn[sp - 1] / 2; n2 -= (n2 & 7);
                    cn = sn[sp - 1] - n2;
                    break;
                } else {
                    val = __fadd_rn(slv[sp - 1], val);
                    sp--;
                }
            }
            if (ret) break;
        } else {
            sn[sp] = cn; sst[sp] = 0; sp++;
            int n2 = cn / 2; n2 -= (n2 & 7);
            cn = n2;
        }
    }
    res = __fadd_rn(__fmul_rn(a[0], b[0]), res);   // first-element init
    if (mode == 0) {
        scal[S_RS] = res; scal[S_DONE] = 0.f; scal[S_DONE2] = 0.f;
    } else if (mode == 1) {
        scal[S_DONE] = scal[S_DONE2];  // done_old for this iteration
        scal[S_ALPHA] = __fdiv_rn(scal[S_RS], __fadd_rn(res, (float)1e-12));
    } else {
        float rs1 = res;
        scal[S_BETA] = __fdiv_rn(rs1, __fadd_rn(scal[S_RS], (float)1e-12));
        float dn = scal[S_DONE];
        if (dn == 0.f) scal[S_RS] = rs1;
        scal[S_DONE2] = (dn != 0.f || __fsqrt_rn(rs1) <= (float)1e-4) ? 1.f : 0.f;
    }
}

// ---------- CSR build (stable in edge order) ----------

__global__ void k_edge_pre(const int* __restrict__ dst, const int* __restrict__ src,
                           const float* __restrict__ ea, float* __restrict__ inv,
                           int* __restrict__ dstCnt, int* __restrict__ srcCnt, int E) {
    int e = blockIdx.x * blockDim.x + threadIdx.x;
    if (e >= E) return;
    float dx = fmaxf(ea[2 * e], 1e-6f);
    inv[e] = __fdiv_rn(1.f, dx);
    atomicAdd(&dstCnt[dst[e]], 1);
    atomicAdd(&srcCnt[src[e]], 1);
}

__global__ void k_scan1(const int* __restrict__ cnt, int* __restrict__ incl,
                        int* __restrict__ bsums, int N) {
    __shared__ int sm[512];
    int i = blockIdx.x * 512 + threadIdx.x;
    sm[threadIdx.x] = (i < N) ? cnt[i] : 0;
    __syncthreads();
    for (int off = 1; off < 512; off <<= 1) {
        int t = (threadIdx.x >= off) ? sm[threadIdx.x - off] : 0;
        __syncthreads();
        sm[threadIdx.x] += t;
        __syncthreads();
    }
    if (i < N) incl[i] = sm[threadIdx.x];
    if (threadIdx.x == 511) bsums[blockIdx.x] = sm[511];
}

__global__ void k_scan2(int* __restrict__ bsums, int nb) {
    __shared__ int sm[512];
    sm[threadIdx.x] = (threadIdx.x < nb) ? bsums[threadIdx.x] : 0;
    __syncthreads();
    for (int off = 1; off < 512; off <<= 1) {
        int t = (threadIdx.x >= off) ? sm[threadIdx.x - off] : 0;
        __syncthreads();
        sm[threadIdx.x] += t;
        __syncthreads();
    }
    if (threadIdx.x < nb) bsums[threadIdx.x] = sm[threadIdx.x];
}

__global__ void k_scan3(int* __restrict__ off, const int* __restrict__ bsums,
                        const int* __restrict__ cnt, int N, int E) {
    int i = blockIdx.x * 512 + threadIdx.x;
    if (i < N) {
        int add = (blockIdx.x > 0) ? bsums[blockIdx.x - 1] : 0;
        off[i] = off[i] + add - cnt[i];  // exclusive
    }
    if (i == 0) off[N] = E;
}

__global__ void k_fill(const int* __restrict__ dst, const int* __restrict__ src,
                       const int* __restrict__ dstOff, const int* __restrict__ srcOff,
                       int* __restrict__ cursD, int* __restrict__ cursS,
                       int* __restrict__ dstList, int* __restrict__ srcList, int E) {
    int e = blockIdx.x * blockDim.x + threadIdx.x;
    if (e >= E) return;
    int d = dst[e];
    dstList[dstOff[d] + atomicAdd(&cursD[d], 1)] = e;
    int s0 = src[e];
    srcList[srcOff[s0] + atomicAdd(&cursS[s0], 1)] = e;
}

__device__ __forceinline__ void insort(int* L, int lo, int hi) {
    for (int a = lo + 1; a < hi; ++a) {
        int key = L[a]; int b = a - 1;
        while (b >= lo && L[b] > key) { L[b + 1] = L[b]; b--; }
        L[b + 1] = key;
    }
}

__global__ void k_sort(const int* __restrict__ dstOff, const int* __restrict__ srcOff,
                       int* __restrict__ dstList, int* __restrict__ srcList, int N) {
    int i = blockIdx.x * blockDim.x + threadIdx.x;
    if (i >= N) return;
    insort(dstList, dstOff[i], dstOff[i + 1]);
    insort(srcList, srcOff[i], srcOff[i + 1]);
}

// ---------- physics kernels (exact np op order, f32 sequential) ----------

// slope_n per node (sequential over dst-edges in edge order); b = u - (dt*g)*slope_n -> r
__global__ void k_slope_b(const float* __restrict__ u, const float* __restrict__ ea,
                          const int* __restrict__ dstOff, const int* __restrict__ dstList,
                          float* __restrict__ r, const float* __restrict__ dtp,
                          const float* __restrict__ gp, int N) {
    int i = blockIdx.x * blockDim.x + threadIdx.x;
    if (i >= N) return;
    float dtg = __fmul_rn(dt_eff_of(dtp), gp[0]);
    float sn = 0.f;
    int k0 = dstOff[i], k1 = dstOff[i + 1];
    for (int k = k0; k < k1; ++k) {
        int e = dstList[k];
        float dx = fmaxf(ea[2 * e], 1e-6f);
        sn = __fadd_rn(sn, __fdiv_rn(ea[2 * e + 1], dx));
    }
    #pragma unroll
    for (int f = 0; f < F; ++f)
        r[i * F + f] = __fsub_rn(u[i * F + f], __fmul_rn(dtg, sn));
}

// s = D1_T(u*y): per (i,f): dst-pass (local) then src-pass (gather), edge order
__global__ void k_d1t(const int* __restrict__ dst, const int* __restrict__ dstOff,
                      const int* __restrict__ dstList, const int* __restrict__ srcOff,
                      const int* __restrict__ srcList, const float* __restrict__ inv,
                      const float* __restrict__ u, const float* __restrict__ y,
                      float* __restrict__ s, int NF) {
    int idx = blockIdx.x * blockDim.x + threadIdx.x;
    if (idx >= NF) return;
    int i = idx >> 3, f = idx & 7;
    float uy = __fmul_rn(u[idx], y[idx]);   // (u*y)[i,f], one rounding as in np temp
    float acc = 0.f;
    int k0 = dstOff[i], k1 = dstOff[i + 1];
    for (int k = k0; k < k1; ++k) {
        int e = dstList[k];
        acc = __fadd_rn(acc, __fmul_rn(uy, inv[e]));
    }
    k0 = srcOff[i]; k1 = srcOff[i + 1];
    for (int k = k0; k < k1; ++k) {
        int e = srcList[k];
        int d = dst[e];
        float yd = __fmul_rn(__fmul_rn(u[d * F + f], y[d * F + f]), inv[e]);
        acc = __fadd_rn(acc, -yd);
    }
    s[idx] = acc;
}

// r = b + dt*s (rhs); p = r; x = 0
__global__ void k_rhs_fin(float* __restrict__ r, float* __restrict__ p,
                          const float* __restrict__ s, float* __restrict__ x,
                          const float* __restrict__ dtp, int NF) {
    int idx = blockIdx.x * blockDim.x + threadIdx.x;
    if (idx >= NF) return;
    float dt = dt_eff_of(dtp);
    float rv = __fadd_rn(r[idx], __fmul_rn(dt, s[idx]));
    r[idx] = rv;
    p[idx] = rv;
    x[idx] = 0.f;
}

// t = D1(p): per (i,f): sum over dst-edges of (p[i]-p[src])*inv, edge order
__global__ void k_d1(const int* __restrict__ src, const int* __restrict__ dstOff,
                     const int* __restrict__ dstList, const float* __restrict__ inv,
                     const float* __restrict__ pv, float* __restrict__ t, int NF) {
    int idx = blockIdx.x * blockDim.x + threadIdx.x;
    if (idx >= NF) return;
    int i = idx >> 3, f = idx & 7;
    float pi = pv[idx];
    float acc = 0.f;
    int k0 = dstOff[i], k1 = dstOff[i + 1];
    for (int k = k0; k < k1; ++k) {
        int e = dstList[k];
        float v = __fmul_rn(__fsub_rn(pi, pv[src[e] * F + f]), inv[e]);
        acc = __fadd_rn(acc, v);
    }
    t[idx] = acc;
}

// w = p + dt*(u*t)
__global__ void k_w(const float* __restrict__ u, const float* __restrict__ pv,
                    const float* __restrict__ t, float* __restrict__ w,
                    const float* __restrict__ dtp, int NF) {
    int idx = blockIdx.x * blockDim.x + threadIdx.x;
    if (idx >= NF) return;
    float dt = dt_eff_of(dtp);
    w[idx] = __fadd_rn(pv[idx], __fmul_rn(dt, __fmul_rn(u[idx], t[idx])));
}

// z = w + dt*s  (stored into t)
__global__ void k_z(const float* __restrict__ w, const float* __restrict__ s,
                    float* __restrict__ t, const float* __restrict__ dtp, int NF) {
    int idx = blockIdx.x * blockDim.x + threadIdx.x;
    if (idx >= NF) return;
    float dt = dt_eff_of(dtp);
    t[idx] = __fadd_rn(w[idx], __fmul_rn(dt, s[idx]));
}

// x += alpha*p ; r -= alpha*z   (guarded by done_old)
__global__ void k_xr(float* __restrict__ x, float* __restrict__ r,
                     const float* __restrict__ pv, const float* __restrict__ z,
                     const float* __restrict__ scal, int NF) {
    int idx = blockIdx.x * blockDim.x + threadIdx.x;
    if (idx >= NF) return;
    if (scal[S_DONE] != 0.f) return;
    float al = scal[S_ALPHA];
    x[idx] = __fadd_rn(x[idx], __fmul_rn(al, pv[idx]));
    r[idx] = __fsub_rn(r[idx], __fmul_rn(al, z[idx]));
}

// p = r + beta*p   (guarded by done_old)
__global__ void k_p(float* __restrict__ pv, const float* __restrict__ r,
                    const float* __restrict__ scal, int NF) {
    int idx = blockIdx.x * blockDim.x + threadIdx.x;
    if (idx >= NF) return;
    if (scal[S_DONE] != 0.f) return;
    pv[idx] = __fadd_rn(r[idx], __fmul_rn(scal[S_BETA], pv[idx]));
}

extern "C" void kernel_launch(void* const* d_in, const int* in_sizes, int n_in,
                              void* d_out, int out_size, void* d_ws, size_t ws_size,
                              hipStream_t stream) {
    const float* u   = (const float*)d_in[0];
    const int*   ei  = (const int*)d_in[1];
    const float* ea  = (const float*)d_in[2];
    const float* dtp = (const float*)d_in[3];
    const float* gp  = (const float*)d_in[4];

    const int NF = in_sizes[0];        // 1,600,000
    const int N  = NF / F;             // 200,000
    const int E  = in_sizes[2] / 2;    // 3,200,000
    const int* srcp = ei;
    const int* dstp = ei + E;

    char* wp = (char*)d_ws;
    float* scal    = (float*)wp; wp += 64 * 4;
    float* r       = (float*)wp; wp += (size_t)NF * 4;
    float* p       = (float*)wp; wp += (size_t)NF * 4;
    float* t       = (float*)wp; wp += (size_t)NF * 4;
    float* w       = (float*)wp; wp += (size_t)NF * 4;
    float* s       = (float*)wp; wp += (size_t)NF * 4;
    float* inv     = (float*)wp; wp += (size_t)E * 4;
    int*   dstList = (int*)wp;   wp += (size_t)E * 4;
    int*   srcList = (int*)wp;   wp += (size_t)E * 4;
    int*   dstOff  = (int*)wp;   wp += (size_t)(N + 1) * 4;
    int*   srcOff  = (int*)wp;   wp += (size_t)(N + 1) * 4;
    int*   dstCnt  = (int*)wp;   wp += (size_t)N * 4;
    int*   srcCnt  = (int*)wp;   wp += (size_t)N * 4;
    int*   cursD   = (int*)wp;   wp += (size_t)N * 4;
    int*   cursS   = (int*)wp;   wp += (size_t)N * 4;
    int*   bsD     = (int*)wp;   wp += 512 * 4;
    int*   bsS     = (int*)wp;   wp += 512 * 4;
    int*   leafOff = (int*)wp;   wp += 2048 * 4;
    int*   leafN   = (int*)wp;   wp += 2048 * 4;
    int*   nLeaf   = (int*)wp;   wp += 64;
    float* partial = (float*)wp; wp += 2048 * 4;
    float* x = (float*)d_out;

    hipMemsetAsync(scal, 0, 64 * 4, stream);
    hipMemsetAsync(dstCnt, 0, (size_t)N * 4, stream);
    hipMemsetAsync(srcCnt, 0, (size_t)N * 4, stream);
    hipMemsetAsync(cursD, 0, (size_t)N * 4, stream);
    hipMemsetAsync(cursS, 0, (size_t)N * 4, stream);

    const int bn = 256;
    const int gNF = (NF + bn - 1) / bn;
    const int gN  = (N + bn - 1) / bn;
    const int gE  = (E + bn - 1) / bn;
    const int nb  = (N + 511) / 512;

    // ---- CSR build (stable by edge id) ----
    k_edge_pre<<<gE, bn, 0, stream>>>(dstp, srcp, ea, inv, dstCnt, srcCnt, E);
    k_scan1<<<nb, 512, 0, stream>>>(dstCnt, dstOff, bsD, N);
    k_scan2<<<1, 512, 0, stream>>>(bsD, nb);
    k_scan3<<<nb, 512, 0, stream>>>(dstOff, bsD, dstCnt, N, E);
    k_scan1<<<nb, 512, 0, stream>>>(srcCnt, srcOff, bsS, N);
    k_scan2<<<1, 512, 0, stream>>>(bsS, nb);
    k_scan3<<<nb, 512, 0, stream>>>(srcOff, bsS, srcCnt, N, E);
    k_fill<<<gE, bn, 0, stream>>>(dstp, srcp, dstOff, srcOff, cursD, cursS,
                                  dstList, srcList, E);
    k_sort<<<gN, bn, 0, stream>>>(dstOff, srcOff, dstList, srcList, N);
    k_build_leaves<<<1, 1, 0, stream>>>(NF - 1, leafOff, leafN, nLeaf);

    // ---- setup: b -> r ; rhs = b + dt*D1T(u*b) ; p=r ; x=0 ; rs0 ----
    k_slope_b<<<gN, bn, 0, stream>>>(u, ea, dstOff, dstList, r, dtp, gp, N);
    k_d1t<<<gNF, bn, 0, stream>>>(dstp, dstOff, dstList, srcOff, srcList, inv,
                                  u, r, s, NF);
    k_rhs_fin<<<gNF, bn, 0, stream>>>(r, p, s, x, dtp, NF);
    k_dot_leaf<<<8, 256, 0, stream>>>(r, r, leafOff, leafN, nLeaf, partial);
    k_dot_combine<<<1, 1, 0, stream>>>(r, r, partial, NF - 1, 0, scal);

    // ---- CG loop ----
    for (int it = 0; it < CG_ITERS; ++it) {
        k_d1<<<gNF, bn, 0, stream>>>(srcp, dstOff, dstList, inv, p, t, NF);
        k_w<<<gNF, bn, 0, stream>>>(u, p, t, w, dtp, NF);
        k_d1t<<<gNF, bn, 0, stream>>>(dstp, dstOff, dstList, srcOff, srcList, inv,
                                      u, w, s, NF);
        k_z<<<gNF, bn, 0, stream>>>(w, s, t, dtp, NF);
        k_dot_leaf<<<8, 256, 0, stream>>>(p, t, leafOff, leafN, nLeaf, partial);
        k_dot_combine<<<1, 1, 0, stream>>>(p, t, partial, NF - 1, 1, scal);
        k_xr<<<gNF, bn, 0, stream>>>(x, r, p, t, scal, NF);
        k_dot_leaf<<<8, 256, 0, stream>>>(r, r, leafOff, leafN, nLeaf, partial);
        k_dot_combine<<<1, 1, 0, stream>>>(r, r, partial, NF - 1, 2, scal);
        k_p<<<gNF, bn, 0, stream>>>(p, r, scal, NF);
    }
}

// Round 10
// 60376.123 us; speedup vs baseline: 1.3054x; 1.3054x over previous
//
#include <hip/hip_runtime.h>
#include <math.h>

// PhysicsLSGStep: bitwise-faithful f32 replication of the numpy reference
// (model H11, PASSED R9 @ absmax 0.484375) + performance restructure.
// All arithmetic orders preserved exactly:
// - np.add.at scatters: per-(node,feat) sequential f32 accumulation in edge
//   order (stable CSR).
// - np.sum: acc init from FIRST element, then numpy pairwise tree over n-1
//   (8-acc base blocks <=128, n2 -= n2%8 splits) — evaluated in parallel by
//   replaying the identical tree (wave-per-leaf + exact combine).
// - elementwise: f32 __f*_rn, no FMA contraction.

#define F 8
#define CG_ITERS 30
#define LEAF_T 4096
#define DOT_NB 800     // grid blocks for k_dot (>= max leaves = ceil(NF/2041))

#define S_RS    0
#define S_ALPHA 1
#define S_BETA  2
#define S_DONE  3
#define S_DONE2 4

__device__ __forceinline__ float dt_eff_of(const float* dtp) {
    return fminf(fmaxf(dtp[0], 0.02f), 2.0f);
}

// ---------- numpy pairwise sum (sum of a[i]*b[i]) ----------

__device__ float pw_base(const float* a, const float* b, int n) {
    if (n < 8) {
        float res = 0.f;
        for (int i = 0; i < n; ++i) res = __fadd_rn(res, __fmul_rn(a[i], b[i]));
        return res;
    }
    float r0 = __fmul_rn(a[0], b[0]);
    float r1 = __fmul_rn(a[1], b[1]);
    float r2 = __fmul_rn(a[2], b[2]);
    float r3 = __fmul_rn(a[3], b[3]);
    float r4 = __fmul_rn(a[4], b[4]);
    float r5 = __fmul_rn(a[5], b[5]);
    float r6 = __fmul_rn(a[6], b[6]);
    float r7 = __fmul_rn(a[7], b[7]);
    int i = 8;
    int lim = n - (n & 7);
    for (; i < lim; i += 8) {
        r0 = __fadd_rn(r0, __fmul_rn(a[i + 0], b[i + 0]));
        r1 = __fadd_rn(r1, __fmul_rn(a[i + 1], b[i + 1]));
        r2 = __fadd_rn(r2, __fmul_rn(a[i + 2], b[i + 2]));
        r3 = __fadd_rn(r3, __fmul_rn(a[i + 3], b[i + 3]));
        r4 = __fadd_rn(r4, __fmul_rn(a[i + 4], b[i + 4]));
        r5 = __fadd_rn(r5, __fmul_rn(a[i + 5], b[i + 5]));
        r6 = __fadd_rn(r6, __fmul_rn(a[i + 6], b[i + 6]));
        r7 = __fadd_rn(r7, __fmul_rn(a[i + 7], b[i + 7]));
    }
    float res = __fadd_rn(__fadd_rn(__fadd_rn(r0, r1), __fadd_rn(r2, r3)),
                          __fadd_rn(__fadd_rn(r4, r5), __fadd_rn(r6, r7)));
    for (; i < n; ++i) res = __fadd_rn(res, __fmul_rn(a[i], b[i]));
    return res;
}

// wave-parallel evaluation of one leaf segment (n0 <= LEAF_T), replaying the
// EXACT recursion: lane L computes the L-th base block (<=128), then all lanes
// replay the combine tree with shuffled base values. off0 physical.
__device__ float leaf_eval_wave(const float* a, const float* b, int off0, int n0,
                                int lane) {
    int myOff = 0, myN = 0;
    {   // pass 1: in-order enumeration of base blocks
        int soff[12], sn[12]; char sst[12];
        int sp = 0, coff = off0, cn = n0, cnt = 0;
        for (;;) {
            if (cn <= 128) {
                if (cnt == lane) { myOff = coff; myN = cn; }
                cnt++;
                bool fin = false;
                for (;;) {
                    if (sp == 0) { fin = true; break; }
                    if (sst[sp - 1] == 0) {
                        sst[sp - 1] = 1;
                        int n2 = sn[sp - 1] / 2; n2 -= (n2 & 7);
                        coff = soff[sp - 1] + n2; cn = sn[sp - 1] - n2;
                        break;
                    } else sp--;
                }
                if (fin) break;
            } else {
                soff[sp] = coff; sn[sp] = cn; sst[sp] = 0; sp++;
                int n2 = cn / 2; n2 -= (n2 & 7);
                cn = n2;
            }
        }
    }
    float bv = (myN > 0) ? pw_base(a + myOff, b + myOff, myN) : 0.f;
    {   // pass 2: replay combine tree (uniform control flow; shfl base vals)
        int sn[12]; char sst[12]; float slv[12];
        int sp = 0, cn = n0, c2 = 0;
        for (;;) {
            if (cn <= 128) {
                float val = __shfl(bv, c2); c2++;
                for (;;) {
                    if (sp == 0) return val;
                    if (sst[sp - 1] == 0) {
                        sst[sp - 1] = 1; slv[sp - 1] = val;
                        int n2 = sn[sp - 1] / 2; n2 -= (n2 & 7);
                        cn = sn[sp - 1] - n2;
                        break;
                    } else { val = __fadd_rn(slv[sp - 1], val); sp--; }
                }
            } else {
                sn[sp] = cn; sst[sp] = 0; sp++;
                int n2 = cn / 2; n2 -= (n2 & 7);
                cn = n2;
            }
        }
    }
}

// leaf decomposition of virtual [0, n) (n = NF-1; physical offset +1)
__global__ void k_build_leaves(int n, int* leafOff, int* leafN, int* nLeaf) {
    if (threadIdx.x != 0 || blockIdx.x != 0) return;
    int spOff[40], spN[40]; int sp = 0;
    spOff[0] = 0; spN[0] = n;
    int cnt = 0;
    while (sp >= 0) {
        int off = spOff[sp], nn = spN[sp]; sp--;
        if (nn <= LEAF_T) {
            if (cnt < 2048) { leafOff[cnt] = off; leafN[cnt] = nn; }
            cnt++;
        } else {
            int n2 = nn / 2; n2 -= (n2 & 7);
            spOff[++sp] = off + n2; spN[sp] = nn - n2;  // right (popped second)
            spOff[++sp] = off;      spN[sp] = n2;       // left  (popped first)
        }
    }
    *nLeaf = cnt;
}

// full dot: wave-per-leaf + last-block upper-tree combine + scalar update.
// blockDim = 64 (one wave). n = NF-1 (virtual), physical offset +1.
__global__ void k_dot(const float* __restrict__ a, const float* __restrict__ b,
                      const int* __restrict__ leafOff, const int* __restrict__ leafN,
                      const int* __restrict__ nLeaf, float* __restrict__ partial,
                      int* __restrict__ ctr, float* __restrict__ scal,
                      int n, int mode, int nBlocks) {
    int j = blockIdx.x;
    int lane = threadIdx.x;
    int NL = *nLeaf;
    if (j < NL) {
        float v = leaf_eval_wave(a, b, leafOff[j] + 1, leafN[j], lane);
        if (lane == 0) partial[j] = v;
    }
    __threadfence();
    __shared__ int isLast;
    if (lane == 0) isLast = (atomicAdd(ctr, 1) == nBlocks - 1) ? 1 : 0;
    __syncthreads();
    if (!isLast) return;
    __threadfence();
    __shared__ float lp[1024];
    for (int k = lane; k < NL; k += 64) lp[k] = partial[k];
    __syncthreads();
    if (lane != 0) return;
    // upper-tree combine (exact pairwise recursion over virtual n, leaves=lp)
    int cnt = 0;
    int sn[24]; char sst[24]; float slv[24];
    int sp = 0, cn = n;
    float res;
    for (;;) {
        if (cn <= LEAF_T) {
            float val = lp[cnt++];
            bool ret = false;
            for (;;) {
                if (sp == 0) { res = val; ret = true; break; }
                if (sst[sp - 1] == 0) {
                    sst[sp - 1] = 1; slv[sp - 1] = val;
                    int n2 = sn[sp - 1] / 2; n2 -= (n2 & 7);
                    cn = sn[sp - 1] - n2;
                    break;
                } else { val = __fadd_rn(slv[sp - 1], val); sp--; }
            }
            if (ret) break;
        } else {
            sn[sp] = cn; sst[sp] = 0; sp++;
            int n2 = cn / 2; n2 -= (n2 & 7);
            cn = n2;
        }
    }
    res = __fadd_rn(__fmul_rn(a[0], b[0]), res);   // first-element init
    if (mode == 0) {
        scal[S_RS] = res; scal[S_DONE] = 0.f; scal[S_DONE2] = 0.f;
    } else if (mode == 1) {
        scal[S_DONE] = scal[S_DONE2];  // done_old for this iteration
        scal[S_ALPHA] = __fdiv_rn(scal[S_RS], __fadd_rn(res, (float)1e-12));
    } else {
        float rs1 = res;
        scal[S_BETA] = __fdiv_rn(rs1, __fadd_rn(scal[S_RS], (float)1e-12));
        float dn = scal[S_DONE];
        if (dn == 0.f) scal[S_RS] = rs1;
        scal[S_DONE2] = (dn != 0.f || __fsqrt_rn(rs1) <= (float)1e-4) ? 1.f : 0.f;
    }
    *ctr = 0;   // reset for next dot in the graph
}

// ---------- CSR build (stable in edge order) ----------

__global__ void k_edge_pre(const int* __restrict__ dst, const int* __restrict__ src,
                           const float* __restrict__ ea, float* __restrict__ inv,
                           int* __restrict__ dstCnt, int* __restrict__ srcCnt, int E) {
    int e = blockIdx.x * blockDim.x + threadIdx.x;
    if (e >= E) return;
    float dx = fmaxf(ea[2 * e], 1e-6f);
    inv[e] = __fdiv_rn(1.f, dx);
    atomicAdd(&dstCnt[dst[e]], 1);
    atomicAdd(&srcCnt[src[e]], 1);
}

__global__ void k_scan1(const int* __restrict__ cnt, int* __restrict__ incl,
                        int* __restrict__ bsums, int N) {
    __shared__ int sm[512];
    int i = blockIdx.x * 512 + threadIdx.x;
    sm[threadIdx.x] = (i < N) ? cnt[i] : 0;
    __syncthreads();
    for (int off = 1; off < 512; off <<= 1) {
        int t = (threadIdx.x >= off) ? sm[threadIdx.x - off] : 0;
        __syncthreads();
        sm[threadIdx.x] += t;
        __syncthreads();
    }
    if (i < N) incl[i] = sm[threadIdx.x];
    if (threadIdx.x == 511) bsums[blockIdx.x] = sm[511];
}

__global__ void k_scan2(int* __restrict__ bsums, int nb) {
    __shared__ int sm[512];
    sm[threadIdx.x] = (threadIdx.x < nb) ? bsums[threadIdx.x] : 0;
    __syncthreads();
    for (int off = 1; off < 512; off <<= 1) {
        int t = (threadIdx.x >= off) ? sm[threadIdx.x - off] : 0;
        __syncthreads();
        sm[threadIdx.x] += t;
        __syncthreads();
    }
    if (threadIdx.x < nb) bsums[threadIdx.x] = sm[threadIdx.x];
}

__global__ void k_scan3(int* __restrict__ off, const int* __restrict__ bsums,
                        const int* __restrict__ cnt, int N, int E) {
    int i = blockIdx.x * 512 + threadIdx.x;
    if (i < N) {
        int add = (blockIdx.x > 0) ? bsums[blockIdx.x - 1] : 0;
        off[i] = off[i] + add - cnt[i];  // exclusive
    }
    if (i == 0) off[N] = E;
}

__global__ void k_fill(const int* __restrict__ dst, const int* __restrict__ src,
                       const int* __restrict__ dstOff, const int* __restrict__ srcOff,
                       int* __restrict__ cursD, int* __restrict__ cursS,
                       int* __restrict__ dstList, int* __restrict__ srcList, int E) {
    int e = blockIdx.x * blockDim.x + threadIdx.x;
    if (e >= E) return;
    int d = dst[e];
    dstList[dstOff[d] + atomicAdd(&cursD[d], 1)] = e;
    int s0 = src[e];
    srcList[srcOff[s0] + atomicAdd(&cursS[s0], 1)] = e;
}

__device__ __forceinline__ void insort(int* L, int lo, int hi) {
    for (int a = lo + 1; a < hi; ++a) {
        int key = L[a]; int b = a - 1;
        while (b >= lo && L[b] > key) { L[b + 1] = L[b]; b--; }
        L[b + 1] = key;
    }
}

__global__ void k_sort(const int* __restrict__ dstOff, const int* __restrict__ srcOff,
                       int* __restrict__ dstList, int* __restrict__ srcList, int N) {
    int i = blockIdx.x * blockDim.x + threadIdx.x;
    if (i >= N) return;
    insort(dstList, dstOff[i], dstOff[i + 1]);
    insort(srcList, srcOff[i], srcOff[i + 1]);
}

// ---------- physics kernels (exact np op order, f32 sequential) ----------

// slope_n (sequential, edge order); b = u - (dt*g)*slope_n -> r ; y = u*b
__global__ void k_slope_b(const float* __restrict__ u, const float* __restrict__ ea,
                          const int* __restrict__ dstOff, const int* __restrict__ dstList,
                          float* __restrict__ r, float* __restrict__ y,
                          const float* __restrict__ dtp, const float* __restrict__ gp,
                          int N) {
    int i = blockIdx.x * blockDim.x + threadIdx.x;
    if (i >= N) return;
    float dtg = __fmul_rn(dt_eff_of(dtp), gp[0]);
    float sn = 0.f;
    int k0 = dstOff[i], k1 = dstOff[i + 1];
    for (int k = k0; k < k1; ++k) {
        int e = dstList[k];
        float dx = fmaxf(ea[2 * e], 1e-6f);
        sn = __fadd_rn(sn, __fdiv_rn(ea[2 * e + 1], dx));
    }
    #pragma unroll
    for (int f = 0; f < F; ++f) {
        float uv = u[i * F + f];
        float bv = __fsub_rn(uv, __fmul_rn(dtg, sn));
        r[i * F + f] = bv;
        y[i * F + f] = __fmul_rn(uv, bv);
    }
}

// D1_T via y (= u*input elementwise, bitwise-identical product), then combine:
// out = base + dt*acc. Used for setup (base=r(b), out=p) and loop (base=w, out=t(z)).
__global__ void k_d1tz(const int* __restrict__ dst, const int* __restrict__ dstOff,
                       const int* __restrict__ dstList, const int* __restrict__ srcOff,
                       const int* __restrict__ srcList, const float* __restrict__ inv,
                       const float* __restrict__ y, const float* __restrict__ base,
                       float* __restrict__ out, const float* __restrict__ dtp, int NF) {
    int idx = blockIdx.x * blockDim.x + threadIdx.x;
    if (idx >= NF) return;
    int i = idx >> 3, f = idx & 7;
    float uy = y[idx];
    float acc = 0.f;
    int k0 = dstOff[i], k1 = dstOff[i + 1];
    for (int k = k0; k < k1; ++k) {
        int e = dstList[k];
        acc = __fadd_rn(acc, __fmul_rn(uy, inv[e]));
    }
    k0 = srcOff[i]; k1 = srcOff[i + 1];
    for (int k = k0; k < k1; ++k) {
        int e = srcList[k];
        int d = dst[e];
        float yd = __fmul_rn(y[d * F + f], inv[e]);
        acc = __fadd_rn(acc, -yd);
    }
    float dt = dt_eff_of(dtp);
    out[idx] = __fadd_rn(base[idx], __fmul_rn(dt, acc));
}

// r = p copy ; x = 0  (float4)
__global__ void k_init(const float4* __restrict__ p4, float4* __restrict__ r4,
                       float4* __restrict__ x4, int n4) {
    int i = blockIdx.x * blockDim.x + threadIdx.x;
    if (i >= n4) return;
    r4[i] = p4[i];
    x4[i] = make_float4(0.f, 0.f, 0.f, 0.f);
}

// D1(p) fused with w = p + dt*(u*t)  and  y = u*w
__global__ void k_d1w(const int* __restrict__ src, const int* __restrict__ dstOff,
                      const int* __restrict__ dstList, const float* __restrict__ inv,
                      const float* __restrict__ pv, const float* __restrict__ u,
                      float* __restrict__ w, float* __restrict__ y,
                      const float* __restrict__ dtp, int NF) {
    int idx = blockIdx.x * blockDim.x + threadIdx.x;
    if (idx >= NF) return;
    int i = idx >> 3, f = idx & 7;
    float pi = pv[idx];
    float acc = 0.f;
    int k0 = dstOff[i], k1 = dstOff[i + 1];
    for (int k = k0; k < k1; ++k) {
        int e = dstList[k];
        float v = __fmul_rn(__fsub_rn(pi, pv[src[e] * F + f]), inv[e]);
        acc = __fadd_rn(acc, v);
    }
    float dt = dt_eff_of(dtp);
    float uv = u[idx];
    float wv = __fadd_rn(pi, __fmul_rn(dt, __fmul_rn(uv, acc)));
    w[idx] = wv;
    y[idx] = __fmul_rn(uv, wv);
}

// x += alpha*p ; r -= alpha*z   (guarded by done_old)  float4
__global__ void k_xr(float4* __restrict__ x4, float4* __restrict__ r4,
                     const float4* __restrict__ p4, const float4* __restrict__ z4,
                     const float* __restrict__ scal, int n4) {
    int i = blockIdx.x * blockDim.x + threadIdx.x;
    if (i >= n4) return;
    if (scal[S_DONE] != 0.f) return;
    float al = scal[S_ALPHA];
    float4 xv = x4[i], pv = p4[i], rv = r4[i], zv = z4[i];
    xv.x = __fadd_rn(xv.x, __fmul_rn(al, pv.x));
    xv.y = __fadd_rn(xv.y, __fmul_rn(al, pv.y));
    xv.z = __fadd_rn(xv.z, __fmul_rn(al, pv.z));
    xv.w = __fadd_rn(xv.w, __fmul_rn(al, pv.w));
    rv.x = __fsub_rn(rv.x, __fmul_rn(al, zv.x));
    rv.y = __fsub_rn(rv.y, __fmul_rn(al, zv.y));
    rv.z = __fsub_rn(rv.z, __fmul_rn(al, zv.z));
    rv.w = __fsub_rn(rv.w, __fmul_rn(al, zv.w));
    x4[i] = xv;
    r4[i] = rv;
}

// p = r + beta*p   (guarded by done_old)  float4
__global__ void k_p(float4* __restrict__ p4, const float4* __restrict__ r4,
                    const float* __restrict__ scal, int n4) {
    int i = blockIdx.x * blockDim.x + threadIdx.x;
    if (i >= n4) return;
    if (scal[S_DONE] != 0.f) return;
    float be = scal[S_BETA];
    float4 pv = p4[i], rv = r4[i];
    pv.x = __fadd_rn(rv.x, __fmul_rn(be, pv.x));
    pv.y = __fadd_rn(rv.y, __fmul_rn(be, pv.y));
    pv.z = __fadd_rn(rv.z, __fmul_rn(be, pv.z));
    pv.w = __fadd_rn(rv.w, __fmul_rn(be, pv.w));
    p4[i] = pv;
}

extern "C" void kernel_launch(void* const* d_in, const int* in_sizes, int n_in,
                              void* d_out, int out_size, void* d_ws, size_t ws_size,
                              hipStream_t stream) {
    const float* u   = (const float*)d_in[0];
    const int*   ei  = (const int*)d_in[1];
    const float* ea  = (const float*)d_in[2];
    const float* dtp = (const float*)d_in[3];
    const float* gp  = (const float*)d_in[4];

    const int NF = in_sizes[0];        // 1,600,000
    const int N  = NF / F;             // 200,000
    const int E  = in_sizes[2] / 2;    // 3,200,000
    const int* srcp = ei;
    const int* dstp = ei + E;

    char* wp = (char*)d_ws;
    float* scal    = (float*)wp; wp += 64 * 4;     // scal[0..7] + ctr @ int slot 32
    float* r       = (float*)wp; wp += (size_t)NF * 4;
    float* p       = (float*)wp; wp += (size_t)NF * 4;
    float* t       = (float*)wp; wp += (size_t)NF * 4;   // z
    float* w       = (float*)wp; wp += (size_t)NF * 4;
    float* y       = (float*)wp; wp += (size_t)NF * 4;   // u*w / u*b
    float* inv     = (float*)wp; wp += (size_t)E * 4;
    int*   dstList = (int*)wp;   wp += (size_t)E * 4;
    int*   srcList = (int*)wp;   wp += (size_t)E * 4;
    int*   dstOff  = (int*)wp;   wp += (size_t)(N + 1) * 4;
    int*   srcOff  = (int*)wp;   wp += (size_t)(N + 1) * 4;
    int*   dstCnt  = (int*)wp;   wp += (size_t)N * 4;
    int*   srcCnt  = (int*)wp;   wp += (size_t)N * 4;
    int*   cursD   = (int*)wp;   wp += (size_t)N * 4;
    int*   cursS   = (int*)wp;   wp += (size_t)N * 4;
    int*   bsD     = (int*)wp;   wp += 512 * 4;
    int*   bsS     = (int*)wp;   wp += 512 * 4;
    int*   leafOff = (int*)wp;   wp += 2048 * 4;
    int*   leafN   = (int*)wp;   wp += 2048 * 4;
    int*   nLeaf   = (int*)wp;   wp += 64;
    float* partial = (float*)wp; wp += 2048 * 4;
    float* x = (float*)d_out;
    int*   ctr = (int*)(scal + 32);

    hipMemsetAsync(scal, 0, 64 * 4, stream);
    hipMemsetAsync(dstCnt, 0, (size_t)N * 4, stream);
    hipMemsetAsync(srcCnt, 0, (size_t)N * 4, stream);
    hipMemsetAsync(cursD, 0, (size_t)N * 4, stream);
    hipMemsetAsync(cursS, 0, (size_t)N * 4, stream);

    const int bn = 256;
    const int gNF = (NF + bn - 1) / bn;
    const int gN  = (N + bn - 1) / bn;
    const int gE  = (E + bn - 1) / bn;
    const int nb  = (N + 511) / 512;
    const int n4  = NF / 4;
    const int g4  = (n4 + bn - 1) / bn;

    // ---- CSR build (stable by edge id) ----
    k_edge_pre<<<gE, bn, 0, stream>>>(dstp, srcp, ea, inv, dstCnt, srcCnt, E);
    k_scan1<<<nb, 512, 0, stream>>>(dstCnt, dstOff, bsD, N);
    k_scan2<<<1, 512, 0, stream>>>(bsD, nb);
    k_scan3<<<nb, 512, 0, stream>>>(dstOff, bsD, dstCnt, N, E);
    k_scan1<<<nb, 512, 0, stream>>>(srcCnt, srcOff, bsS, N);
    k_scan2<<<1, 512, 0, stream>>>(bsS, nb);
    k_scan3<<<nb, 512, 0, stream>>>(srcOff, bsS, srcCnt, N, E);
    k_fill<<<gE, bn, 0, stream>>>(dstp, srcp, dstOff, srcOff, cursD, cursS,
                                  dstList, srcList, E);
    k_sort<<<gN, bn, 0, stream>>>(dstOff, srcOff, dstList, srcList, N);
    k_build_leaves<<<1, 1, 0, stream>>>(NF - 1, leafOff, leafN, nLeaf);

    // ---- setup: b->r, y=u*b ; p = b + dt*D1T(y) ; r=p, x=0 ; rs0 = p.p ----
    k_slope_b<<<gN, bn, 0, stream>>>(u, ea, dstOff, dstList, r, y, dtp, gp, N);
    k_d1tz<<<gNF, bn, 0, stream>>>(dstp, dstOff, dstList, srcOff, srcList, inv,
                                   y, r, p, dtp, NF);
    k_init<<<g4, bn, 0, stream>>>((const float4*)p, (float4*)r, (float4*)x, n4);
    k_dot<<<DOT_NB, 64, 0, stream>>>(p, p, leafOff, leafN, nLeaf, partial, ctr,
                                     scal, NF - 1, 0, DOT_NB);

    // ---- CG loop ----
    for (int it = 0; it < CG_ITERS; ++it) {
        k_d1w<<<gNF, bn, 0, stream>>>(srcp, dstOff, dstList, inv, p, u, w, y,
                                      dtp, NF);
        k_d1tz<<<gNF, bn, 0, stream>>>(dstp, dstOff, dstList, srcOff, srcList,
                                       inv, y, w, t, dtp, NF);
        k_dot<<<DOT_NB, 64, 0, stream>>>(p, t, leafOff, leafN, nLeaf, partial,
                                         ctr, scal, NF - 1, 1, DOT_NB);
        k_xr<<<g4, bn, 0, stream>>>((float4*)x, (float4*)r, (const float4*)p,
                                    (const float4*)t, scal, n4);
        k_dot<<<DOT_NB, 64, 0, stream>>>(r, r, leafOff, leafN, nLeaf, partial,
                                         ctr, scal, NF - 1, 2, DOT_NB);
        k_p<<<g4, bn, 0, stream>>>((float4*)p, (const float4*)r, scal, n4);
    }
}

// Round 11
// 25911.874 us; speedup vs baseline: 3.0416x; 2.3301x over previous
//
#include <hip/hip_runtime.h>
#include <math.h>

// PhysicsLSGStep: bitwise-faithful f32 replication of the numpy reference
// (model H11, PASSED R9/R10 @ absmax 0.484375).
// R11: k_dot de-scratched — all dynamically-indexed tree-walk stacks moved to
// LDS (dynamic-index private arrays spill to scratch/global => ~1ms/dot and
// multi-ms outliers in R10 profile). Arithmetic order is UNCHANGED:
// - np.add.at scatters: per-(node,feat) sequential f32, edge order (CSR).
// - np.sum: acc init from FIRST element + numpy pairwise tree over n-1
//   (8-acc base blocks <=128, n2 -= n2%8 splits), replayed exactly.
// - elementwise: f32 __f*_rn, no FMA contraction.

#define F 8
#define CG_ITERS 30
#define LEAF_T 4096
#define DOT_NB 800     // >= max leaves (NL <= ~781 for NF-1 = 1,599,999)

#define S_RS    0
#define S_ALPHA 1
#define S_BETA  2
#define S_DONE  3
#define S_DONE2 4

__device__ __forceinline__ float dt_eff_of(const float* dtp) {
    return fminf(fmaxf(dtp[0], 0.02f), 2.0f);
}

// ---------- numpy pairwise sum base block (sum of a[i]*b[i], n<=128) ----------

__device__ float pw_base(const float* a, const float* b, int n) {
    if (n < 8) {
        float res = 0.f;
        for (int i = 0; i < n; ++i) res = __fadd_rn(res, __fmul_rn(a[i], b[i]));
        return res;
    }
    float r0 = __fmul_rn(a[0], b[0]);
    float r1 = __fmul_rn(a[1], b[1]);
    float r2 = __fmul_rn(a[2], b[2]);
    float r3 = __fmul_rn(a[3], b[3]);
    float r4 = __fmul_rn(a[4], b[4]);
    float r5 = __fmul_rn(a[5], b[5]);
    float r6 = __fmul_rn(a[6], b[6]);
    float r7 = __fmul_rn(a[7], b[7]);
    int i = 8;
    int lim = n - (n & 7);
    for (; i < lim; i += 8) {
        r0 = __fadd_rn(r0, __fmul_rn(a[i + 0], b[i + 0]));
        r1 = __fadd_rn(r1, __fmul_rn(a[i + 1], b[i + 1]));
        r2 = __fadd_rn(r2, __fmul_rn(a[i + 2], b[i + 2]));
        r3 = __fadd_rn(r3, __fmul_rn(a[i + 3], b[i + 3]));
        r4 = __fadd_rn(r4, __fmul_rn(a[i + 4], b[i + 4]));
        r5 = __fadd_rn(r5, __fmul_rn(a[i + 5], b[i + 5]));
        r6 = __fadd_rn(r6, __fmul_rn(a[i + 6], b[i + 6]));
        r7 = __fadd_rn(r7, __fmul_rn(a[i + 7], b[i + 7]));
    }
    float res = __fadd_rn(__fadd_rn(__fadd_rn(r0, r1), __fadd_rn(r2, r3)),
                          __fadd_rn(__fadd_rn(r4, r5), __fadd_rn(r6, r7)));
    for (; i < n; ++i) res = __fadd_rn(res, __fmul_rn(a[i], b[i]));
    return res;
}

// leaf decomposition of virtual [0, n) (n = NF-1; physical offset +1).
// Single thread; stacks in LDS (avoid scratch).
__global__ void k_build_leaves(int n, int* leafOff, int* leafN, int* nLeaf) {
    __shared__ int spOff[40], spN[40];
    if (threadIdx.x != 0 || blockIdx.x != 0) return;
    int sp = 0;
    spOff[0] = 0; spN[0] = n;
    int cnt = 0;
    while (sp >= 0) {
        int off = spOff[sp], nn = spN[sp]; sp--;
        if (nn <= LEAF_T) {
            if (cnt < 2048) { leafOff[cnt] = off; leafN[cnt] = nn; }
            cnt++;
        } else {
            int n2 = nn / 2; n2 -= (n2 & 7);
            spOff[++sp] = off + n2; spN[sp] = nn - n2;  // right (popped second)
            spOff[++sp] = off;      spN[sp] = n2;       // left  (popped first)
        }
    }
    *nLeaf = cnt;
}

// full dot: one wave per leaf + last-block upper-tree combine + scalar update.
// All tree-walk stacks in LDS. blockDim = 64. n = NF-1 (virtual), phys +1.
__global__ void k_dot(const float* __restrict__ a, const float* __restrict__ b,
                      const int* __restrict__ leafOff, const int* __restrict__ leafN,
                      const int* __restrict__ nLeaf, float* __restrict__ partial,
                      int* __restrict__ ctr, float* __restrict__ scal,
                      int n, int mode, int nBlocks) {
    __shared__ int   sOff[64], sN[64];     // base blocks of this leaf (<=64)
    __shared__ float sBase[64];            // base-block partial values
    __shared__ int   wSo[16], wSn[16], wSt[16];
    __shared__ float wVal[16];
    __shared__ int   sNB;
    __shared__ int   isLast;
    __shared__ float lp[1024];
    __shared__ int   cSn[24], cSt[24];
    __shared__ float cVal[24];

    int j = blockIdx.x, lane = threadIdx.x;
    int NL = *nLeaf;
    if (j < NL) {
        if (lane == 0) {
            // phase 1: enumerate base blocks in order (LDS stack)
            int coff = leafOff[j] + 1, cn = leafN[j];
            int sp = 0, cnt = 0;
            for (;;) {
                if (cn <= 128) {
                    sOff[cnt] = coff; sN[cnt] = cn; cnt++;
                    bool fin = false;
                    for (;;) {
                        if (sp == 0) { fin = true; break; }
                        if (wSt[sp - 1] == 0) {
                            wSt[sp - 1] = 1;
                            int n2 = wSn[sp - 1] / 2; n2 -= (n2 & 7);
                            coff = wSo[sp - 1] + n2; cn = wSn[sp - 1] - n2;
                            break;
                        } else sp--;
                    }
                    if (fin) break;
                } else {
                    wSo[sp] = coff; wSn[sp] = cn; wSt[sp] = 0; sp++;
                    int n2 = cn / 2; n2 -= (n2 & 7);
                    cn = n2;
                }
            }
            sNB = cnt;
        }
        __syncthreads();
        int NB = sNB;
        if (lane < NB) sBase[lane] = pw_base(a + sOff[lane], b + sOff[lane], sN[lane]);
        __syncthreads();
        if (lane == 0) {
            // phase 2: replay combine tree, popping base values in order
            int sp = 0, cn = leafN[j], c2 = 0;
            float res;
            for (;;) {
                if (cn <= 128) {
                    float val = sBase[c2++];
                    bool done = false;
                    for (;;) {
                        if (sp == 0) { res = val; done = true; break; }
                        if (wSt[sp - 1] == 0) {
                            wSt[sp - 1] = 1; wVal[sp - 1] = val;
                            int n2 = wSn[sp - 1] / 2; n2 -= (n2 & 7);
                            cn = wSn[sp - 1] - n2;
                            break;
                        } else { val = __fadd_rn(wVal[sp - 1], val); sp--; }
                    }
                    if (done) break;
                } else {
                    wSn[sp] = cn; wSt[sp] = 0; sp++;
                    int n2 = cn / 2; n2 -= (n2 & 7);
                    cn = n2;
                }
            }
            partial[j] = res;
        }
    }
    __threadfence();
    if (lane == 0) isLast = (atomicAdd(ctr, 1) == nBlocks - 1) ? 1 : 0;
    __syncthreads();
    if (!isLast) return;
    __threadfence();
    for (int k = lane; k < NL; k += 64) lp[k] = partial[k];
    __syncthreads();
    if (lane != 0) return;
    // upper-tree combine (exact pairwise recursion over virtual n, leaves=lp)
    int cnt = 0;
    int sp = 0, cn = n;
    float res;
    for (;;) {
        if (cn <= LEAF_T) {
            float val = lp[cnt++];
            bool ret = false;
            for (;;) {
                if (sp == 0) { res = val; ret = true; break; }
                if (cSt[sp - 1] == 0) {
                    cSt[sp - 1] = 1; cVal[sp - 1] = val;
                    int n2 = cSn[sp - 1] / 2; n2 -= (n2 & 7);
                    cn = cSn[sp - 1] - n2;
                    break;
                } else { val = __fadd_rn(cVal[sp - 1], val); sp--; }
            }
            if (ret) break;
        } else {
            cSn[sp] = cn; cSt[sp] = 0; sp++;
            int n2 = cn / 2; n2 -= (n2 & 7);
            cn = n2;
        }
    }
    res = __fadd_rn(__fmul_rn(a[0], b[0]), res);   // first-element init
    if (mode == 0) {
        scal[S_RS] = res; scal[S_DONE] = 0.f; scal[S_DONE2] = 0.f;
    } else if (mode == 1) {
        scal[S_DONE] = scal[S_DONE2];  // done_old for this iteration
        scal[S_ALPHA] = __fdiv_rn(scal[S_RS], __fadd_rn(res, (float)1e-12));
    } else {
        float rs1 = res;
        scal[S_BETA] = __fdiv_rn(rs1, __fadd_rn(scal[S_RS], (float)1e-12));
        float dn = scal[S_DONE];
        if (dn == 0.f) scal[S_RS] = rs1;
        scal[S_DONE2] = (dn != 0.f || __fsqrt_rn(rs1) <= (float)1e-4) ? 1.f : 0.f;
    }
    *ctr = 0;   // reset for next dot in the graph
}

// ---------- CSR build (stable in edge order) ----------

__global__ void k_edge_pre(const int* __restrict__ dst, const int* __restrict__ src,
                           const float* __restrict__ ea, float* __restrict__ inv,
                           int* __restrict__ dstCnt, int* __restrict__ srcCnt, int E) {
    int e = blockIdx.x * blockDim.x + threadIdx.x;
    if (e >= E) return;
    float dx = fmaxf(ea[2 * e], 1e-6f);
    inv[e] = __fdiv_rn(1.f, dx);
    atomicAdd(&dstCnt[dst[e]], 1);
    atomicAdd(&srcCnt[src[e]], 1);
}

__global__ void k_scan1(const int* __restrict__ cnt, int* __restrict__ incl,
                        int* __restrict__ bsums, int N) {
    __shared__ int sm[512];
    int i = blockIdx.x * 512 + threadIdx.x;
    sm[threadIdx.x] = (i < N) ? cnt[i] : 0;
    __syncthreads();
    for (int off = 1; off < 512; off <<= 1) {
        int t = (threadIdx.x >= off) ? sm[threadIdx.x - off] : 0;
        __syncthreads();
        sm[threadIdx.x] += t;
        __syncthreads();
    }
    if (i < N) incl[i] = sm[threadIdx.x];
    if (threadIdx.x == 511) bsums[blockIdx.x] = sm[511];
}

__global__ void k_scan2(int* __restrict__ bsums, int nb) {
    __shared__ int sm[512];
    sm[threadIdx.x] = (threadIdx.x < nb) ? bsums[threadIdx.x] : 0;
    __syncthreads();
    for (int off = 1; off < 512; off <<= 1) {
        int t = (threadIdx.x >= off) ? sm[threadIdx.x - off] : 0;
        __syncthreads();
        sm[threadIdx.x] += t;
        __syncthreads();
    }
    if (threadIdx.x < nb) bsums[threadIdx.x] = sm[threadIdx.x];
}

__global__ void k_scan3(int* __restrict__ off, const int* __restrict__ bsums,
                        const int* __restrict__ cnt, int N, int E) {
    int i = blockIdx.x * 512 + threadIdx.x;
    if (i < N) {
        int add = (blockIdx.x > 0) ? bsums[blockIdx.x - 1] : 0;
        off[i] = off[i] + add - cnt[i];  // exclusive
    }
    if (i == 0) off[N] = E;
}

__global__ void k_fill(const int* __restrict__ dst, const int* __restrict__ src,
                       const int* __restrict__ dstOff, const int* __restrict__ srcOff,
                       int* __restrict__ cursD, int* __restrict__ cursS,
                       int* __restrict__ dstList, int* __restrict__ srcList, int E) {
    int e = blockIdx.x * blockDim.x + threadIdx.x;
    if (e >= E) return;
    int d = dst[e];
    dstList[dstOff[d] + atomicAdd(&cursD[d], 1)] = e;
    int s0 = src[e];
    srcList[srcOff[s0] + atomicAdd(&cursS[s0], 1)] = e;
}

__device__ __forceinline__ void insort(int* L, int lo, int hi) {
    for (int a = lo + 1; a < hi; ++a) {
        int key = L[a]; int b = a - 1;
        while (b >= lo && L[b] > key) { L[b + 1] = L[b]; b--; }
        L[b + 1] = key;
    }
}

__global__ void k_sort(const int* __restrict__ dstOff, const int* __restrict__ srcOff,
                       int* __restrict__ dstList, int* __restrict__ srcList, int N) {
    int i = blockIdx.x * blockDim.x + threadIdx.x;
    if (i >= N) return;
    insort(dstList, dstOff[i], dstOff[i + 1]);
    insort(srcList, srcOff[i], srcOff[i + 1]);
}

// ---------- physics kernels (exact np op order, f32 sequential) ----------

// slope_n (sequential, edge order); b = u - (dt*g)*slope_n -> r ; y = u*b
__global__ void k_slope_b(const float* __restrict__ u, const float* __restrict__ ea,
                          const int* __restrict__ dstOff, const int* __restrict__ dstList,
                          float* __restrict__ r, float* __restrict__ y,
                          const float* __restrict__ dtp, const float* __restrict__ gp,
                          int N) {
    int i = blockIdx.x * blockDim.x + threadIdx.x;
    if (i >= N) return;
    float dtg = __fmul_rn(dt_eff_of(dtp), gp[0]);
    float sn = 0.f;
    int k0 = dstOff[i], k1 = dstOff[i + 1];
    for (int k = k0; k < k1; ++k) {
        int e = dstList[k];
        float dx = fmaxf(ea[2 * e], 1e-6f);
        sn = __fadd_rn(sn, __fdiv_rn(ea[2 * e + 1], dx));
    }
    #pragma unroll
    for (int f = 0; f < F; ++f) {
        float uv = u[i * F + f];
        float bv = __fsub_rn(uv, __fmul_rn(dtg, sn));
        r[i * F + f] = bv;
        y[i * F + f] = __fmul_rn(uv, bv);
    }
}

// D1_T via y (= u*input, bitwise-identical product), then out = base + dt*acc.
// Setup: base=r(b), out=p. Loop: base=w, out=t(z).
__global__ void k_d1tz(const int* __restrict__ dst, const int* __restrict__ dstOff,
                       const int* __restrict__ dstList, const int* __restrict__ srcOff,
                       const int* __restrict__ srcList, const float* __restrict__ inv,
                       const float* __restrict__ y, const float* __restrict__ base,
                       float* __restrict__ out, const float* __restrict__ dtp, int NF) {
    int idx = blockIdx.x * blockDim.x + threadIdx.x;
    if (idx >= NF) return;
    int i = idx >> 3, f = idx & 7;
    float uy = y[idx];
    float acc = 0.f;
    int k0 = dstOff[i], k1 = dstOff[i + 1];
    for (int k = k0; k < k1; ++k) {
        int e = dstList[k];
        acc = __fadd_rn(acc, __fmul_rn(uy, inv[e]));
    }
    k0 = srcOff[i]; k1 = srcOff[i + 1];
    for (int k = k0; k < k1; ++k) {
        int e = srcList[k];
        int d = dst[e];
        float yd = __fmul_rn(y[d * F + f], inv[e]);
        acc = __fadd_rn(acc, -yd);
    }
    float dt = dt_eff_of(dtp);
    out[idx] = __fadd_rn(base[idx], __fmul_rn(dt, acc));
}

// r = p copy ; x = 0  (float4)
__global__ void k_init(const float4* __restrict__ p4, float4* __restrict__ r4,
                       float4* __restrict__ x4, int n4) {
    int i = blockIdx.x * blockDim.x + threadIdx.x;
    if (i >= n4) return;
    r4[i] = p4[i];
    x4[i] = make_float4(0.f, 0.f, 0.f, 0.f);
}

// D1(p) fused with w = p + dt*(u*t)  and  y = u*w
__global__ void k_d1w(const int* __restrict__ src, const int* __restrict__ dstOff,
                      const int* __restrict__ dstList, const float* __restrict__ inv,
                      const float* __restrict__ pv, const float* __restrict__ u,
                      float* __restrict__ w, float* __restrict__ y,
                      const float* __restrict__ dtp, int NF) {
    int idx = blockIdx.x * blockDim.x + threadIdx.x;
    if (idx >= NF) return;
    int i = idx >> 3, f = idx & 7;
    float pi = pv[idx];
    float acc = 0.f;
    int k0 = dstOff[i], k1 = dstOff[i + 1];
    for (int k = k0; k < k1; ++k) {
        int e = dstList[k];
        float v = __fmul_rn(__fsub_rn(pi, pv[src[e] * F + f]), inv[e]);
        acc = __fadd_rn(acc, v);
    }
    float dt = dt_eff_of(dtp);
    float uv = u[idx];
    float wv = __fadd_rn(pi, __fmul_rn(dt, __fmul_rn(uv, acc)));
    w[idx] = wv;
    y[idx] = __fmul_rn(uv, wv);
}

// x += alpha*p ; r -= alpha*z   (guarded by done_old)  float4
__global__ void k_xr(float4* __restrict__ x4, float4* __restrict__ r4,
                     const float4* __restrict__ p4, const float4* __restrict__ z4,
                     const float* __restrict__ scal, int n4) {
    int i = blockIdx.x * blockDim.x + threadIdx.x;
    if (i >= n4) return;
    if (scal[S_DONE] != 0.f) return;
    float al = scal[S_ALPHA];
    float4 xv = x4[i], pv = p4[i], rv = r4[i], zv = z4[i];
    xv.x = __fadd_rn(xv.x, __fmul_rn(al, pv.x));
    xv.y = __fadd_rn(xv.y, __fmul_rn(al, pv.y));
    xv.z = __fadd_rn(xv.z, __fmul_rn(al, pv.z));
    xv.w = __fadd_rn(xv.w, __fmul_rn(al, pv.w));
    rv.x = __fsub_rn(rv.x, __fmul_rn(al, zv.x));
    rv.y = __fsub_rn(rv.y, __fmul_rn(al, zv.y));
    rv.z = __fsub_rn(rv.z, __fmul_rn(al, zv.z));
    rv.w = __fsub_rn(rv.w, __fmul_rn(al, zv.w));
    x4[i] = xv;
    r4[i] = rv;
}

// p = r + beta*p   (guarded by done_old)  float4
__global__ void k_p(float4* __restrict__ p4, const float4* __restrict__ r4,
                    const float* __restrict__ scal, int n4) {
    int i = blockIdx.x * blockDim.x + threadIdx.x;
    if (i >= n4) return;
    if (scal[S_DONE] != 0.f) return;
    float be = scal[S_BETA];
    float4 pv = p4[i], rv = r4[i];
    pv.x = __fadd_rn(rv.x, __fmul_rn(be, pv.x));
    pv.y = __fadd_rn(rv.y, __fmul_rn(be, pv.y));
    pv.z = __fadd_rn(rv.z, __fmul_rn(be, pv.z));
    pv.w = __fadd_rn(rv.w, __fmul_rn(be, pv.w));
    p4[i] = pv;
}

extern "C" void kernel_launch(void* const* d_in, const int* in_sizes, int n_in,
                              void* d_out, int out_size, void* d_ws, size_t ws_size,
                              hipStream_t stream) {
    const float* u   = (const float*)d_in[0];
    const int*   ei  = (const int*)d_in[1];
    const float* ea  = (const float*)d_in[2];
    const float* dtp = (const float*)d_in[3];
    const float* gp  = (const float*)d_in[4];

    const int NF = in_sizes[0];        // 1,600,000
    const int N  = NF / F;             // 200,000
    const int E  = in_sizes[2] / 2;    // 3,200,000
    const int* srcp = ei;
    const int* dstp = ei + E;

    char* wp = (char*)d_ws;
    float* scal    = (float*)wp; wp += 64 * 4;     // scal[0..7] + ctr @ int slot 32
    float* r       = (float*)wp; wp += (size_t)NF * 4;
    float* p       = (float*)wp; wp += (size_t)NF * 4;
    float* t       = (float*)wp; wp += (size_t)NF * 4;   // z
    float* w       = (float*)wp; wp += (size_t)NF * 4;
    float* y       = (float*)wp; wp += (size_t)NF * 4;   // u*w / u*b
    float* inv     = (float*)wp; wp += (size_t)E * 4;
    int*   dstList = (int*)wp;   wp += (size_t)E * 4;
    int*   srcList = (int*)wp;   wp += (size_t)E * 4;
    int*   dstOff  = (int*)wp;   wp += (size_t)(N + 1) * 4;
    int*   srcOff  = (int*)wp;   wp += (size_t)(N + 1) * 4;
    int*   dstCnt  = (int*)wp;   wp += (size_t)N * 4;
    int*   srcCnt  = (int*)wp;   wp += (size_t)N * 4;
    int*   cursD   = (int*)wp;   wp += (size_t)N * 4;
    int*   cursS   = (int*)wp;   wp += (size_t)N * 4;
    int*   bsD     = (int*)wp;   wp += 512 * 4;
    int*   bsS     = (int*)wp;   wp += 512 * 4;
    int*   leafOff = (int*)wp;   wp += 2048 * 4;
    int*   leafN   = (int*)wp;   wp += 2048 * 4;
    int*   nLeaf   = (int*)wp;   wp += 64;
    float* partial = (float*)wp; wp += 2048 * 4;
    float* x = (float*)d_out;
    int*   ctr = (int*)(scal + 32);

    hipMemsetAsync(scal, 0, 64 * 4, stream);
    hipMemsetAsync(dstCnt, 0, (size_t)N * 4, stream);
    hipMemsetAsync(srcCnt, 0, (size_t)N * 4, stream);
    hipMemsetAsync(cursD, 0, (size_t)N * 4, stream);
    hipMemsetAsync(cursS, 0, (size_t)N * 4, stream);

    const int bn = 256;
    const int gNF = (NF + bn - 1) / bn;
    const int gN  = (N + bn - 1) / bn;
    const int gE  = (E + bn - 1) / bn;
    const int nb  = (N + 511) / 512;
    const int n4  = NF / 4;
    const int g4  = (n4 + bn - 1) / bn;

    // ---- CSR build (stable by edge id) ----
    k_edge_pre<<<gE, bn, 0, stream>>>(dstp, srcp, ea, inv, dstCnt, srcCnt, E);
    k_scan1<<<nb, 512, 0, stream>>>(dstCnt, dstOff, bsD, N);
    k_scan2<<<1, 512, 0, stream>>>(bsD, nb);
    k_scan3<<<nb, 512, 0, stream>>>(dstOff, bsD, dstCnt, N, E);
    k_scan1<<<nb, 512, 0, stream>>>(srcCnt, srcOff, bsS, N);
    k_scan2<<<1, 512, 0, stream>>>(bsS, nb);
    k_scan3<<<nb, 512, 0, stream>>>(srcOff, bsS, srcCnt, N, E);
    k_fill<<<gE, bn, 0, stream>>>(dstp, srcp, dstOff, srcOff, cursD, cursS,
                                  dstList, srcList, E);
    k_sort<<<gN, bn, 0, stream>>>(dstOff, srcOff, dstList, srcList, N);
    k_build_leaves<<<1, 64, 0, stream>>>(NF - 1, leafOff, leafN, nLeaf);

    // ---- setup: b->r, y=u*b ; p = b + dt*D1T(y) ; r=p, x=0 ; rs0 = p.p ----
    k_slope_b<<<gN, bn, 0, stream>>>(u, ea, dstOff, dstList, r, y, dtp, gp, N);
    k_d1tz<<<gNF, bn, 0, stream>>>(dstp, dstOff, dstList, srcOff, srcList, inv,
                                   y, r, p, dtp, NF);
    k_init<<<g4, bn, 0, stream>>>((const float4*)p, (float4*)r, (float4*)x, n4);
    k_dot<<<DOT_NB, 64, 0, stream>>>(p, p, leafOff, leafN, nLeaf, partial, ctr,
                                     scal, NF - 1, 0, DOT_NB);

    // ---- CG loop ----
    for (int it = 0; it < CG_ITERS; ++it) {
        k_d1w<<<gNF, bn, 0, stream>>>(srcp, dstOff, dstList, inv, p, u, w, y,
                                      dtp, NF);
        k_d1tz<<<gNF, bn, 0, stream>>>(dstp, dstOff, dstList, srcOff, srcList,
                                       inv, y, w, t, dtp, NF);
        k_dot<<<DOT_NB, 64, 0, stream>>>(p, t, leafOff, leafN, nLeaf, partial,
                                         ctr, scal, NF - 1, 1, DOT_NB);
        k_xr<<<g4, bn, 0, stream>>>((float4*)x, (float4*)r, (const float4*)p,
                                    (const float4*)t, scal, n4);
        k_dot<<<DOT_NB, 64, 0, stream>>>(r, r, leafOff, leafN, nLeaf, partial,
                                         ctr, scal, NF - 1, 2, DOT_NB);
        k_p<<<g4, bn, 0, stream>>>((float4*)p, (const float4*)r, scal, n4);
    }
}